// Round 8
// baseline (299.097 us; speedup 1.0000x reference)
//
#include <hip/hip_runtime.h>
#include <hip/hip_fp8.h>

#define C_ 512
#define T_ 2048
#define N_TOK 16384
#define K_CB 4096

typedef __attribute__((ext_vector_type(16))) float f32x16;

static __device__ __forceinline__ unsigned char f2fp8(float f) {
    __hip_fp8_e4m3 v(f);                 // OCP e4m3, RNE + saturate
    return (unsigned char)v.__x;
}

// ---------------- Kernel 1: transpose student (B,C,T)->(N,C) fp8 + per-token partial stats ------
__global__ __launch_bounds__(256) void k1_prep(
    const float* __restrict__ student,   // (B,C,T) fp32
    const int* __restrict__ codes,       // (B,T) int32
    const float* __restrict__ codebook,  // (K,C) fp32
    unsigned char* __restrict__ A8,      // (N,C) fp8 out
    float* __restrict__ xnorm, float* __restrict__ dtg2)
{
    __shared__ float tile[64][65];
    __shared__ int lcodes[64];
    int tid = threadIdx.x;
    int tnum  = blockIdx.x >> 1;
    int chalf = blockIdx.x & 1;
    int b  = tnum >> 5;
    int t0 = (tnum & 31) << 6;
    int cbase = chalf << 8;             // 0 or 256
    int cx = tid & 63;                  // lane
    int q  = tid >> 6;                  // wave
    if (tid < 64) lcodes[tid] = codes[b * T_ + t0 + tid];
    __syncthreads();
    float ax2[16], ad2[16];
#pragma unroll
    for (int p = 0; p < 16; ++p) { ax2[p] = 0.f; ad2[p] = 0.f; }
    for (int c0 = cbase; c0 < cbase + 256; c0 += 64) {
#pragma unroll
        for (int p = 0; p < 16; ++p) {
            int ch = p * 4 + q;
            tile[ch][cx] = student[(size_t)b * (C_ * T_) + (size_t)(c0 + ch) * T_ + t0 + cx];
        }
        __syncthreads();
#pragma unroll
        for (int p = 0; p < 16; ++p) {
            int ty = p * 4 + q;
            float x = tile[cx][ty];
            int n = b * T_ + t0 + ty;
            A8[(size_t)n * C_ + c0 + cx] = f2fp8(x);
            ax2[p] += x * x;
            float cb = codebook[(size_t)lcodes[ty] * C_ + c0 + cx];
            float d = x - cb;
            ad2[p] += d * d;
        }
        __syncthreads();
    }
#pragma unroll
    for (int p = 0; p < 16; ++p) {
        float sx = ax2[p], sd = ad2[p];
#pragma unroll
        for (int m = 1; m < 64; m <<= 1) {
            sx += __shfl_xor(sx, m);
            sd += __shfl_xor(sd, m);
        }
        if (cx == 0) {
            int n = b * T_ + t0 + p * 4 + q;
            atomicAdd(&xnorm[n], sx);
            atomicAdd(&dtg2[n], sd);
        }
    }
}

// ---------------- Kernel 1b: codebook -> fp8 + row norms + init of all reduce buffers -----------
__global__ __launch_bounds__(256) void k1_cb(
    const float* __restrict__ codebook,
    unsigned char* __restrict__ B8,
    float* __restrict__ cbnorm,
    float* __restrict__ s_sum,
    unsigned* __restrict__ minpack,
    float* __restrict__ xnorm, float* __restrict__ dtg2,
    float* __restrict__ accum)
{
    int tid = threadIdx.x;
    int gidx = blockIdx.x * 256 + tid;
    if (gidx < N_TOK) {
        s_sum[gidx] = 0.f; minpack[gidx] = 0xFFFFFFFFu;
        xnorm[gidx] = 0.f; dtg2[gidx] = 0.f;
    }
    if (gidx < 8) accum[gidx] = 0.f;
    int lane = tid & 63;
    int w = tid >> 6;
    int row = blockIdx.x * 4 + w;
    const float* src = codebook + (size_t)row * C_ + lane * 8;
    float4 v0 = *(const float4*)(src);
    float4 v1 = *(const float4*)(src + 4);
    float s = v0.x*v0.x + v0.y*v0.y + v0.z*v0.z + v0.w*v0.w
            + v1.x*v1.x + v1.y*v1.y + v1.z*v1.z + v1.w*v1.w;
    unsigned lo = (unsigned)f2fp8(v0.x) | ((unsigned)f2fp8(v0.y) << 8)
                | ((unsigned)f2fp8(v0.z) << 16) | ((unsigned)f2fp8(v0.w) << 24);
    unsigned hi = (unsigned)f2fp8(v1.x) | ((unsigned)f2fp8(v1.y) << 8)
                | ((unsigned)f2fp8(v1.z) << 16) | ((unsigned)f2fp8(v1.w) << 24);
    *(uint2*)(B8 + (size_t)row * C_ + lane * 8) = make_uint2(lo, hi);
#pragma unroll
    for (int m = 1; m < 64; m <<= 1) s += __shfl_xor(s, m);
    if (lane == 0) cbnorm[row] = s;
}

// ---------------- Kernel 2: register-resident codebook, barrier-free streaming fp8 MFMA ---------
// Wave owns a 32-col codebook strip: B-frags for K=512 = 32 x 8B = 64 VGPR, loaded ONCE.
// Streams 32-row A-tiles: per tile 32 global dwordx2 + 32 x mfma_32x32x16_fp8 (swapped operands:
// D[i=cb-col][j=student-row]) -> per-lane epilogue, 1 shfl, LDS-atomic accumulate. No barriers
// in the main loop, no LDS staging. grid = 512 (16 row-chunks x 32 col-groups, XCD-chunked:
// per XCD A 2x512KB + B 2MB fits L2). block = 256 = 4 waves = 4 adjacent col-strips.
__global__ __launch_bounds__(256, 2) void k2_main(
    const unsigned char* __restrict__ A8,
    const unsigned char* __restrict__ B8,
    const float* __restrict__ xnorm,
    const float* __restrict__ dtg2,
    const float* __restrict__ cbnorm,
    float* __restrict__ s_sum,
    unsigned* __restrict__ minpack)
{
    __shared__ float lds_s[1024];
    __shared__ unsigned lds_m[1024];
    int tid = threadIdx.x;
    int lane = tid & 63;
    int w = tid >> 6;
    int l31 = lane & 31;
    int hk = (lane >> 5) * 8;            // byte offset of this lane's K-half within a 16B chunk

    // XCD-chunked decomposition: xcd gets 2 row-chunks x all 32 col-groups
    int orig = blockIdx.x;               // 0..511
    int xcd = orig & 7;
    int idx = orig >> 3;                 // 0..63
    int rowchunk = xcd * 2 + (idx >> 5); // 0..15
    int colgroup = idx & 31;             // 0..31
    int row0 = rowchunk * 1024;
    int col0 = colgroup * 128 + w * 32;  // this wave's 32 cb-cols

    for (int i = tid; i < 1024; i += 256) { lds_s[i] = 0.f; lds_m[i] = 0xFFFFFFFFu; }
    __syncthreads();

    // ---- codebook strip into registers (once): B_op lane layout = {col=l31, k-half=lane>>5} ----
    const unsigned char* pB = B8 + (size_t)(col0 + l31) * C_ + hk;
    long bF[32];
#pragma unroll
    for (int ks = 0; ks < 32; ++ks)
        bF[ks] = *(const long*)(pB + ks * 16);

    // per-lane cb-col norms for the 16 acc regs: col = col0 + (r&3) + 8*(r>>2) + 4*(lane>>5)
    float cbn[16];
    int cbase_l = col0 + 4 * (lane >> 5);
#pragma unroll
    for (int r = 0; r < 16; ++r)
        cbn[r] = cbnorm[cbase_l + (r & 3) + 8 * (r >> 2)];

    const unsigned char* pA0 = A8 + (size_t)(row0 + l31) * C_ + hk;

    // prologue: tile 0 both halves into u/v
    long u[16], v[16];
#pragma unroll
    for (int i = 0; i < 16; ++i) u[i] = *(const long*)(pA0 + i * 16);
#pragma unroll
    for (int i = 0; i < 16; ++i) v[i] = *(const long*)(pA0 + 256 + i * 16);

    for (int rt = 0; rt < 32; ++rt) {
        f32x16 acc0, acc1;
#pragma unroll
        for (int r = 0; r < 16; ++r) { acc0[r] = 0.f; acc1[r] = 0.f; }

        const unsigned char* pAn = pA0 + (size_t)(rt + 1) * (32 * C_);
        // ---- MFMA half 0 (u), two independent acc chains ----
#pragma unroll
        for (int i = 0; i < 16; i += 2) {
            acc0 = __builtin_amdgcn_mfma_f32_32x32x16_fp8_fp8(bF[i],     u[i],     acc0, 0, 0, 0);
            acc1 = __builtin_amdgcn_mfma_f32_32x32x16_fp8_fp8(bF[i + 1], u[i + 1], acc1, 0, 0, 0);
        }
        // refill u with next tile's half 0 (latency hidden by half-1 MFMAs + epilogue)
        if (rt < 31) {
#pragma unroll
            for (int i = 0; i < 16; ++i) u[i] = *(const long*)(pAn + i * 16);
        }
        // ---- MFMA half 1 (v) ----
#pragma unroll
        for (int i = 0; i < 16; i += 2) {
            acc0 = __builtin_amdgcn_mfma_f32_32x32x16_fp8_fp8(bF[16 + i],     v[i],     acc0, 0, 0, 0);
            acc1 = __builtin_amdgcn_mfma_f32_32x32x16_fp8_fp8(bF[16 + i + 1], v[i + 1], acc1, 0, 0, 0);
        }
        if (rt < 31) {
#pragma unroll
            for (int i = 0; i < 16; ++i) v[i] = *(const long*)(pAn + 256 + i * 16);
        }

        // ---- epilogue: lane holds 16 cb-cols x 1 student row (row = row0+rt*32+l31) ----
        int lrow = rt * 32 + l31;
        float xn = xnorm[row0 + lrow];
        float dt = sqrtf(dtg2[row0 + lrow]);
        float sv = 0.f;
        unsigned kmin = 0xFFFFFFFFu;
#pragma unroll
        for (int r = 0; r < 16; ++r) {
            float dot = acc0[r] + acc1[r];
            float d2 = fmaxf(fmaf(-2.f, dot, xn) + cbn[r], 0.f);
            float d = sqrtf(d2);
            sv += __expf(fminf(dt - d, 80.f));
            unsigned key = (__float_as_uint(d) & 0xFFFFF000u)
                         | (unsigned)(cbase_l + (r & 3) + 8 * (r >> 2));
            kmin = min(kmin, key);
        }
        sv += __shfl_xor(sv, 32);                    // combine the two cb-col half-sets
        unsigned ok = __shfl_xor(kmin, 32);
        kmin = min(kmin, ok);
        if (lane < 32) {
            atomicAdd(&lds_s[lrow], sv);             // ds_add_f32, 32 consecutive addrs
            atomicMin(&lds_m[lrow], kmin);           // ds_min_u32
        }
    }

    __syncthreads();
    for (int i = tid; i < 1024; i += 256) {
        atomicAdd(&s_sum[row0 + i], lds_s[i]);
        atomicMin(&minpack[row0 + i], lds_m[i]);
    }
}

// ---------------- Kernel 3a: per-token CE/accuracy/emb-loss/target-dist reduce ----------------
__global__ __launch_bounds__(256) void k3a(
    const float* __restrict__ s_sum,
    const unsigned* __restrict__ minpack,
    const int* __restrict__ codes,
    const float* __restrict__ dtg2,
    float* __restrict__ accum)
{
    __shared__ float w0[4], w1[4], w2[4], w3[4];
    int tid = threadIdx.x;
    int n = blockIdx.x * 256 + tid;
    float ce = logf(s_sum[n]);           // = d_t + lse(-d) = per-token CE
    unsigned pred = minpack[n] & 0xFFFu; // col id lives in the low 12 bits
    float ok = (pred == (unsigned)codes[n]) ? 1.f : 0.f;
    float sq = dtg2[n];
    float td = sqrtf(sq);
#pragma unroll
    for (int m = 1; m < 64; m <<= 1) {
        ce += __shfl_xor(ce, m);
        ok += __shfl_xor(ok, m);
        sq += __shfl_xor(sq, m);
        td += __shfl_xor(td, m);
    }
    int lane = tid & 63, w = tid >> 6;
    if (lane == 0) { w0[w] = ce; w1[w] = ok; w2[w] = sq; w3[w] = td; }
    __syncthreads();
    if (tid == 0) {
        atomicAdd(&accum[0], w0[0] + w0[1] + w0[2] + w0[3]);
        atomicAdd(&accum[1], w1[0] + w1[1] + w1[2] + w1[3]);
        atomicAdd(&accum[2], w2[0] + w2[1] + w2[2] + w2[3]);
        atomicAdd(&accum[3], w3[0] + w3[1] + w3[2] + w3[3]);
    }
}

// ---------------- Kernel 3b: finalize 5 outputs ----------------
__global__ void k3b(const float* __restrict__ accum, float* __restrict__ out)
{
    if (threadIdx.x == 0 && blockIdx.x == 0) {
        float ce   = accum[0] / (float)N_TOK;
        float accy = accum[1] / (float)N_TOK;
        float emb  = accum[2] / ((float)N_TOK * (float)C_);
        float td   = accum[3] / (float)N_TOK;
        out[0] = emb + ce;   // total_loss (EMB_W=CE_W=1)
        out[1] = emb;        // emb_to_codebook_loss
        out[2] = ce;         // ce_loss
        out[3] = accy;       // token_accuracy
        out[4] = td;         // emb_to_target_dist
    }
}

extern "C" void kernel_launch(void* const* d_in, const int* in_sizes, int n_in,
                              void* d_out, int out_size, void* d_ws, size_t ws_size,
                              hipStream_t stream)
{
    const float* student  = (const float*)d_in[0];
    const int*   codes    = (const int*)d_in[1];
    const float* codebook = (const float*)d_in[2];
    // d_in[3] distance_matrix is unused by the reference.
    float* out = (float*)d_out;

    char* ws = (char*)d_ws;
    unsigned char* A8     = (unsigned char*)(ws);                  // 8 MiB
    unsigned char* B8     = (unsigned char*)(ws + 8388608);        // 2 MiB
    float* xnorm          = (float*)(ws + 10485760);               // 64 KiB
    float* dtg2           = (float*)(ws + 10551296);               // 64 KiB
    float* cbnorm         = (float*)(ws + 10616832);               // 16 KiB
    float* s_sum          = (float*)(ws + 10633216);               // 64 KiB
    unsigned* minpack     = (unsigned*)(ws + 10698752);            // 64 KiB
    float* accum          = (float*)(ws + 10829824);               // 64 B

    // k1_cb zero-inits s_sum/minpack/xnorm/dtg2/accum (stream-ordered before k1_prep's atomics)
    hipLaunchKernelGGL(k1_cb, dim3(1024), dim3(256), 0, stream,
                       codebook, B8, cbnorm, s_sum, minpack, xnorm, dtg2, accum);
    hipLaunchKernelGGL(k1_prep, dim3(512), dim3(256), 0, stream,
                       student, codes, codebook, A8, xnorm, dtg2);
    hipLaunchKernelGGL(k2_main, dim3(512), dim3(256), 0, stream,
                       A8, B8, xnorm, dtg2, cbnorm, s_sum, minpack);
    hipLaunchKernelGGL(k3a, dim3(64), dim3(256), 0, stream,
                       s_sum, minpack, codes, dtg2, accum);
    hipLaunchKernelGGL(k3b, dim3(1), dim3(64), 0, stream, accum, out);
}

// Round 9
// 146.008 us; speedup vs baseline: 2.0485x; 2.0485x over previous
//
#include <hip/hip_runtime.h>
#include <hip/hip_fp8.h>

#define C_ 512
#define T_ 2048
#define N_TOK 16384
#define K_CB 4096

typedef __attribute__((ext_vector_type(16))) float f32x16;

static __device__ __forceinline__ unsigned char f2fp8(float f) {
    __hip_fp8_e4m3 v(f);                 // OCP e4m3, RNE + saturate
    return (unsigned char)v.__x;
}

typedef const __attribute__((address_space(1))) void* gas_t;
typedef __attribute__((address_space(3))) void* las_t;
static __device__ __forceinline__ void stage16(const void* g, void* l) {
    __builtin_amdgcn_global_load_lds((gas_t)g, (las_t)l, 16, 0, 0);
}

// ---------------- Kernel 1: transpose student (B,C,T)->(N,C) fp8 + per-token partial stats ------
__global__ __launch_bounds__(256) void k1_prep(
    const float* __restrict__ student,   // (B,C,T) fp32
    const int* __restrict__ codes,       // (B,T) int32
    const float* __restrict__ codebook,  // (K,C) fp32
    unsigned char* __restrict__ A8,      // (N,C) fp8 out
    float* __restrict__ xnorm, float* __restrict__ dtg2)
{
    __shared__ float tile[64][65];
    __shared__ int lcodes[64];
    int tid = threadIdx.x;
    int tnum  = blockIdx.x >> 1;
    int chalf = blockIdx.x & 1;
    int b  = tnum >> 5;
    int t0 = (tnum & 31) << 6;
    int cbase = chalf << 8;             // 0 or 256
    int cx = tid & 63;                  // lane
    int q  = tid >> 6;                  // wave
    if (tid < 64) lcodes[tid] = codes[b * T_ + t0 + tid];
    __syncthreads();
    float ax2[16], ad2[16];
#pragma unroll
    for (int p = 0; p < 16; ++p) { ax2[p] = 0.f; ad2[p] = 0.f; }
    for (int c0 = cbase; c0 < cbase + 256; c0 += 64) {
#pragma unroll
        for (int p = 0; p < 16; ++p) {
            int ch = p * 4 + q;
            tile[ch][cx] = student[(size_t)b * (C_ * T_) + (size_t)(c0 + ch) * T_ + t0 + cx];
        }
        __syncthreads();
#pragma unroll
        for (int p = 0; p < 16; ++p) {
            int ty = p * 4 + q;
            float x = tile[cx][ty];
            int n = b * T_ + t0 + ty;
            A8[(size_t)n * C_ + c0 + cx] = f2fp8(x);
            ax2[p] += x * x;
            float cb = codebook[(size_t)lcodes[ty] * C_ + c0 + cx];
            float d = x - cb;
            ad2[p] += d * d;
        }
        __syncthreads();
    }
#pragma unroll
    for (int p = 0; p < 16; ++p) {
        float sx = ax2[p], sd = ad2[p];
#pragma unroll
        for (int m = 1; m < 64; m <<= 1) {
            sx += __shfl_xor(sx, m);
            sd += __shfl_xor(sd, m);
        }
        if (cx == 0) {
            int n = b * T_ + t0 + p * 4 + q;
            atomicAdd(&xnorm[n], sx);
            atomicAdd(&dtg2[n], sd);
        }
    }
}

// ---------------- Kernel 1b: codebook -> fp8 + row norms + init of all reduce buffers -----------
__global__ __launch_bounds__(256) void k1_cb(
    const float* __restrict__ codebook,
    unsigned char* __restrict__ B8,
    float* __restrict__ cbnorm,
    float* __restrict__ s_sum,
    unsigned* __restrict__ minpack,
    float* __restrict__ xnorm, float* __restrict__ dtg2,
    float* __restrict__ accum)
{
    int tid = threadIdx.x;
    int gidx = blockIdx.x * 256 + tid;
    if (gidx < N_TOK) {
        s_sum[gidx] = 0.f; minpack[gidx] = 0xFFFFFFFFu;
        xnorm[gidx] = 0.f; dtg2[gidx] = 0.f;
    }
    if (gidx < 8) accum[gidx] = 0.f;
    int lane = tid & 63;
    int w = tid >> 6;
    int row = blockIdx.x * 4 + w;
    const float* src = codebook + (size_t)row * C_ + lane * 8;
    float4 v0 = *(const float4*)(src);
    float4 v1 = *(const float4*)(src + 4);
    float s = v0.x*v0.x + v0.y*v0.y + v0.z*v0.z + v0.w*v0.w
            + v1.x*v1.x + v1.y*v1.y + v1.z*v1.z + v1.w*v1.w;
    unsigned lo = (unsigned)f2fp8(v0.x) | ((unsigned)f2fp8(v0.y) << 8)
                | ((unsigned)f2fp8(v0.z) << 16) | ((unsigned)f2fp8(v0.w) << 24);
    unsigned hi = (unsigned)f2fp8(v1.x) | ((unsigned)f2fp8(v1.y) << 8)
                | ((unsigned)f2fp8(v1.z) << 16) | ((unsigned)f2fp8(v1.w) << 24);
    *(uint2*)(B8 + (size_t)row * C_ + lane * 8) = make_uint2(lo, hi);
#pragma unroll
    for (int m = 1; m < 64; m <<= 1) s += __shfl_xor(s, m);
    if (lane == 0) cbnorm[row] = s;
}

// ---------------- Kernel 2: A-resident-LDS + streamed-B fp8 32x32 MFMA, swapped operands --------
// grid = 512 (256 row-strips x 2 col-halves, XCD-chunked); block = 256 (4 waves).
// WG: 64 student rows (A 64x512 fp8 = 32KB LDS, staged ONCE) x 2048 cb-cols.
// Flat 64-step loop (8 cc-chunks x 8 k-tiles); B tile 256x64 fp8 = 16KB, double-buffered;
// ONE barrier per step (dbuf makes the 2nd redundant); stage(t+1) issued right after it.
// Swapped mfma(cb, student): lane holds 16 cb-cols per acc for ONE student row -> in-register
// epilogue + 1 shfl. Granule-XOR swizzles (source-side, w16-compatible) -> 4-way max conflicts.
__global__ __launch_bounds__(256, 2) void k2_main(
    const unsigned char* __restrict__ A8,
    const unsigned char* __restrict__ B8,
    const float* __restrict__ xnorm,
    const float* __restrict__ dtg2,
    const float* __restrict__ cbnorm,
    float* __restrict__ s_sum,
    unsigned* __restrict__ minpack)
{
    __shared__ __align__(16) unsigned char aL[32768];      // A: 64 rows x 512B
    __shared__ __align__(16) unsigned char bL[2][16384];   // B: 256 rows x 64B, dbuf
    int tid = threadIdx.x;
    int lane = tid & 63;
    int w = tid >> 6;                    // 0..3: wave owns cb-cols [w*64, w*64+64) of each cc
    int l31 = lane & 31;
    int hk = (lane >> 5) * 8;            // k-half byte offset

    int orig = blockIdx.x;               // 512 = 8 XCD x 64
    int swz = (orig & 7) * 64 + (orig >> 3);
    int strip = swz >> 1;                // 0..255
    int chalf = swz & 1;
    int row0 = strip * 64;
    int cbase = chalf * 2048;

    // ---- stage A once: LDS granule li=(i*256+tid): row R=li>>5, granule M=li&31,
    //      source granule M ^ (R&7)  (inverse-swizzled source, linear dest) ----
#pragma unroll
    for (int i = 0; i < 8; ++i) {
        int li = i * 256 + tid;
        int R = li >> 5;
        int Ms = (li & 31) ^ (R & 7);
        stage16(A8 + (size_t)(row0 + R) * C_ + Ms * 16, aL + li * 16);
    }
#define STAGE_B(bi, tt_) do {                                                 \
        int cb0_ = cbase + ((tt_) >> 3) * 256;                                \
        int ko_ = ((tt_) & 7) * 64;                                           \
        _Pragma("unroll")                                                     \
        for (int i_ = 0; i_ < 4; ++i_) {                                      \
            int li_ = i_ * 256 + tid;                                         \
            int R_ = li_ >> 2;                                                \
            int G_ = (li_ & 3) ^ ((R_ >> 1) & 3);                             \
            stage16(B8 + (size_t)(cb0_ + R_) * C_ + ko_ + G_ * 16,            \
                    bL[bi] + li_ * 16);                                       \
        }                                                                     \
    } while (0)

    STAGE_B(0, 0);
    STAGE_B(1, 1);

    float xn0 = xnorm[row0 + l31],        xn1 = xnorm[row0 + 32 + l31];
    float dt0 = sqrtf(dtg2[row0 + l31]),  dt1 = sqrtf(dtg2[row0 + 32 + l31]);
    float sv0 = 0.f, sv1 = 0.f;
    unsigned km0 = 0xFFFFFFFFu, km1 = 0xFFFFFFFFu;

    f32x16 acc00, acc01, acc10, acc11;    // [rt][ct]
#pragma unroll
    for (int r = 0; r < 16; ++r) { acc00[r]=0.f; acc01[r]=0.f; acc10[r]=0.f; acc11[r]=0.f; }

    // read-address constants
    int ax = l31 & 7;                     // A swizzle term (row&7 == l31&7 for both rt)
    int aB0 = l31 * 512 + hk;             // rt=0 row base
    int aB1 = (32 + l31) * 512 + hk;      // rt=1
    int bR0 = w * 64 + l31;               // ct=0 B-row
    int bR1 = bR0 + 32;                   // ct=1
    int bx0 = (bR0 >> 1) & 3, bx1 = (bR1 >> 1) & 3;
    int bB0 = bR0 * 64 + hk, bB1 = bR1 * 64 + hk;

    for (int cc = 0; cc < 8; ++cc) {
#pragma unroll
        for (int kt = 0; kt < 8; ++kt) {
            int tt = cc * 8 + kt;
            __syncthreads();                          // buf[tt&1] ready; prior reads done
            if (tt < 63) STAGE_B((tt + 1) & 1, tt + 1);
            const unsigned char* bT = bL[tt & 1];
            long aF0[4], aF1[4], bF0[4], bF1[4];
#pragma unroll
            for (int ksl = 0; ksl < 4; ++ksl) {
                int m = kt * 4 + ksl;
                int asw = ((m ^ ax) * 16);
                aF0[ksl] = *(const long*)(aL + aB0 + asw);
                aF1[ksl] = *(const long*)(aL + aB1 + asw);
                bF0[ksl] = *(const long*)(bT + bB0 + ((ksl ^ bx0) * 16));
                bF1[ksl] = *(const long*)(bT + bB1 + ((ksl ^ bx1) * 16));
            }
            __builtin_amdgcn_s_setprio(1);
#pragma unroll
            for (int ksl = 0; ksl < 4; ++ksl) {
                acc00 = __builtin_amdgcn_mfma_f32_32x32x16_fp8_fp8(bF0[ksl], aF0[ksl], acc00, 0, 0, 0);
                acc01 = __builtin_amdgcn_mfma_f32_32x32x16_fp8_fp8(bF1[ksl], aF0[ksl], acc01, 0, 0, 0);
                acc10 = __builtin_amdgcn_mfma_f32_32x32x16_fp8_fp8(bF0[ksl], aF1[ksl], acc10, 0, 0, 0);
                acc11 = __builtin_amdgcn_mfma_f32_32x32x16_fp8_fp8(bF1[ksl], aF1[ksl], acc11, 0, 0, 0);
            }
            __builtin_amdgcn_s_setprio(0);
        }
        // ---- per-cc epilogue: lane = one student row per rt; 16 cb-cols per acc reg-set ----
        int cS = cbase + cc * 256 + w * 64 + 4 * (lane >> 5);
#pragma unroll
        for (int r = 0; r < 16; ++r) {
            int cofs = (r & 3) + 8 * (r >> 2);
            {   // ct = 0
                int col = cS + cofs;
                float cbn = cbnorm[col];
                float d0 = sqrtf(fmaxf(fmaf(-2.f, acc00[r], xn0) + cbn, 0.f));
                sv0 += __expf(fminf(dt0 - d0, 80.f));
                km0 = min(km0, (__float_as_uint(d0) & 0xFFFFF000u) | (unsigned)col);
                float d1 = sqrtf(fmaxf(fmaf(-2.f, acc10[r], xn1) + cbn, 0.f));
                sv1 += __expf(fminf(dt1 - d1, 80.f));
                km1 = min(km1, (__float_as_uint(d1) & 0xFFFFF000u) | (unsigned)col);
            }
            {   // ct = 1
                int col = cS + 32 + cofs;
                float cbn = cbnorm[col];
                float d0 = sqrtf(fmaxf(fmaf(-2.f, acc01[r], xn0) + cbn, 0.f));
                sv0 += __expf(fminf(dt0 - d0, 80.f));
                km0 = min(km0, (__float_as_uint(d0) & 0xFFFFF000u) | (unsigned)col);
                float d1 = sqrtf(fmaxf(fmaf(-2.f, acc11[r], xn1) + cbn, 0.f));
                sv1 += __expf(fminf(dt1 - d1, 80.f));
                km1 = min(km1, (__float_as_uint(d1) & 0xFFFFF000u) | (unsigned)col);
            }
            acc00[r] = 0.f; acc01[r] = 0.f; acc10[r] = 0.f; acc11[r] = 0.f;
        }
    }
#undef STAGE_B

    // merge k-halves (lane vs lane+32 hold disjoint cb-col quads of the same row)
    sv0 += __shfl_xor(sv0, 32);
    sv1 += __shfl_xor(sv1, 32);
    km0 = min(km0, (unsigned)__shfl_xor((int)km0, 32));
    km1 = min(km1, (unsigned)__shfl_xor((int)km1, 32));
    if (lane < 32) {
        atomicAdd(&s_sum[row0 + l31], sv0);
        atomicMin(&minpack[row0 + l31], km0);
        atomicAdd(&s_sum[row0 + 32 + l31], sv1);
        atomicMin(&minpack[row0 + 32 + l31], km1);
    }
}

// ---------------- Kernel 3a: per-token CE/accuracy/emb-loss/target-dist reduce ----------------
__global__ __launch_bounds__(256) void k3a(
    const float* __restrict__ s_sum,
    const unsigned* __restrict__ minpack,
    const int* __restrict__ codes,
    const float* __restrict__ dtg2,
    float* __restrict__ accum)
{
    __shared__ float w0[4], w1[4], w2[4], w3[4];
    int tid = threadIdx.x;
    int n = blockIdx.x * 256 + tid;
    float ce = logf(s_sum[n]);           // = d_t + lse(-d) = per-token CE
    unsigned pred = minpack[n] & 0xFFFu; // col id in the low 12 bits
    float ok = (pred == (unsigned)codes[n]) ? 1.f : 0.f;
    float sq = dtg2[n];
    float td = sqrtf(sq);
#pragma unroll
    for (int m = 1; m < 64; m <<= 1) {
        ce += __shfl_xor(ce, m);
        ok += __shfl_xor(ok, m);
        sq += __shfl_xor(sq, m);
        td += __shfl_xor(td, m);
    }
    int lane = tid & 63, w = tid >> 6;
    if (lane == 0) { w0[w] = ce; w1[w] = ok; w2[w] = sq; w3[w] = td; }
    __syncthreads();
    if (tid == 0) {
        atomicAdd(&accum[0], w0[0] + w0[1] + w0[2] + w0[3]);
        atomicAdd(&accum[1], w1[0] + w1[1] + w1[2] + w1[3]);
        atomicAdd(&accum[2], w2[0] + w2[1] + w2[2] + w2[3]);
        atomicAdd(&accum[3], w3[0] + w3[1] + w3[2] + w3[3]);
    }
}

// ---------------- Kernel 3b: finalize 5 outputs ----------------
__global__ void k3b(const float* __restrict__ accum, float* __restrict__ out)
{
    if (threadIdx.x == 0 && blockIdx.x == 0) {
        float ce   = accum[0] / (float)N_TOK;
        float accy = accum[1] / (float)N_TOK;
        float emb  = accum[2] / ((float)N_TOK * (float)C_);
        float td   = accum[3] / (float)N_TOK;
        out[0] = emb + ce;   // total_loss (EMB_W=CE_W=1)
        out[1] = emb;        // emb_to_codebook_loss
        out[2] = ce;         // ce_loss
        out[3] = accy;       // token_accuracy
        out[4] = td;         // emb_to_target_dist
    }
}

extern "C" void kernel_launch(void* const* d_in, const int* in_sizes, int n_in,
                              void* d_out, int out_size, void* d_ws, size_t ws_size,
                              hipStream_t stream)
{
    const float* student  = (const float*)d_in[0];
    const int*   codes    = (const int*)d_in[1];
    const float* codebook = (const float*)d_in[2];
    // d_in[3] distance_matrix is unused by the reference.
    float* out = (float*)d_out;

    char* ws = (char*)d_ws;
    unsigned char* A8     = (unsigned char*)(ws);                  // 8 MiB
    unsigned char* B8     = (unsigned char*)(ws + 8388608);        // 2 MiB
    float* xnorm          = (float*)(ws + 10485760);               // 64 KiB
    float* dtg2           = (float*)(ws + 10551296);               // 64 KiB
    float* cbnorm         = (float*)(ws + 10616832);               // 16 KiB
    float* s_sum          = (float*)(ws + 10633216);               // 64 KiB
    unsigned* minpack     = (unsigned*)(ws + 10698752);            // 64 KiB
    float* accum          = (float*)(ws + 10829824);               // 64 B

    // k1_cb zero-inits s_sum/minpack/xnorm/dtg2/accum (stream-ordered before k1_prep's atomics)
    hipLaunchKernelGGL(k1_cb, dim3(1024), dim3(256), 0, stream,
                       codebook, B8, cbnorm, s_sum, minpack, xnorm, dtg2, accum);
    hipLaunchKernelGGL(k1_prep, dim3(512), dim3(256), 0, stream,
                       student, codes, codebook, A8, xnorm, dtg2);
    hipLaunchKernelGGL(k2_main, dim3(512), dim3(256), 0, stream,
                       A8, B8, xnorm, dtg2, cbnorm, s_sum, minpack);
    hipLaunchKernelGGL(k3a, dim3(64), dim3(256), 0, stream,
                       s_sum, minpack, codes, dtg2, accum);
    hipLaunchKernelGGL(k3b, dim3(1), dim3(64), 0, stream, accum, out);
}

// Round 10
// 141.335 us; speedup vs baseline: 2.1162x; 1.0331x over previous
//
#include <hip/hip_runtime.h>
#include <hip/hip_fp8.h>

#define C_ 512
#define T_ 2048
#define N_TOK 16384
#define K_CB 4096

typedef __attribute__((ext_vector_type(16))) float f32x16;

static __device__ __forceinline__ unsigned char f2fp8(float f) {
    __hip_fp8_e4m3 v(f);                 // OCP e4m3, RNE + saturate
    return (unsigned char)v.__x;
}

typedef const __attribute__((address_space(1))) void* gas_t;
typedef __attribute__((address_space(3))) void* las_t;
static __device__ __forceinline__ void stage16(const void* g, void* l) {
    __builtin_amdgcn_global_load_lds((gas_t)g, (las_t)l, 16, 0, 0);
}

// ---------------- Kernel 1: transpose student (B,C,T)->(N,C) fp8 + per-token partial stats ------
__global__ __launch_bounds__(256) void k1_prep(
    const float* __restrict__ student,   // (B,C,T) fp32
    const int* __restrict__ codes,       // (B,T) int32
    const float* __restrict__ codebook,  // (K,C) fp32
    unsigned char* __restrict__ A8,      // (N,C) fp8 out
    float* __restrict__ xnorm, float* __restrict__ dtg2)
{
    __shared__ float tile[64][65];
    __shared__ int lcodes[64];
    int tid = threadIdx.x;
    int tnum  = blockIdx.x >> 1;
    int chalf = blockIdx.x & 1;
    int b  = tnum >> 5;
    int t0 = (tnum & 31) << 6;
    int cbase = chalf << 8;             // 0 or 256
    int cx = tid & 63;                  // lane
    int q  = tid >> 6;                  // wave
    if (tid < 64) lcodes[tid] = codes[b * T_ + t0 + tid];
    __syncthreads();
    float ax2[16], ad2[16];
#pragma unroll
    for (int p = 0; p < 16; ++p) { ax2[p] = 0.f; ad2[p] = 0.f; }
    for (int c0 = cbase; c0 < cbase + 256; c0 += 64) {
#pragma unroll
        for (int p = 0; p < 16; ++p) {
            int ch = p * 4 + q;
            tile[ch][cx] = student[(size_t)b * (C_ * T_) + (size_t)(c0 + ch) * T_ + t0 + cx];
        }
        __syncthreads();
#pragma unroll
        for (int p = 0; p < 16; ++p) {
            int ty = p * 4 + q;
            float x = tile[cx][ty];
            int n = b * T_ + t0 + ty;
            A8[(size_t)n * C_ + c0 + cx] = f2fp8(x);
            ax2[p] += x * x;
            float cb = codebook[(size_t)lcodes[ty] * C_ + c0 + cx];
            float d = x - cb;
            ad2[p] += d * d;
        }
        __syncthreads();
    }
#pragma unroll
    for (int p = 0; p < 16; ++p) {
        float sx = ax2[p], sd = ad2[p];
#pragma unroll
        for (int m = 1; m < 64; m <<= 1) {
            sx += __shfl_xor(sx, m);
            sd += __shfl_xor(sd, m);
        }
        if (cx == 0) {
            int n = b * T_ + t0 + p * 4 + q;
            atomicAdd(&xnorm[n], sx);
            atomicAdd(&dtg2[n], sd);
        }
    }
}

// ---------------- Kernel 1b: codebook -> fp8 + row norms + init of all reduce buffers -----------
__global__ __launch_bounds__(256) void k1_cb(
    const float* __restrict__ codebook,
    unsigned char* __restrict__ B8,
    float* __restrict__ cbnorm,
    float* __restrict__ s_sum,
    unsigned* __restrict__ minpack,
    float* __restrict__ xnorm, float* __restrict__ dtg2,
    float* __restrict__ accum)
{
    int tid = threadIdx.x;
    int gidx = blockIdx.x * 256 + tid;
    if (gidx < N_TOK) {
        s_sum[gidx] = 0.f; minpack[gidx] = 0xFFFFFFFFu;
        xnorm[gidx] = 0.f; dtg2[gidx] = 0.f;
    }
    if (gidx < 8) accum[gidx] = 0.f;
    int lane = tid & 63;
    int w = tid >> 6;
    int row = blockIdx.x * 4 + w;
    const float* src = codebook + (size_t)row * C_ + lane * 8;
    float4 v0 = *(const float4*)(src);
    float4 v1 = *(const float4*)(src + 4);
    float s = v0.x*v0.x + v0.y*v0.y + v0.z*v0.z + v0.w*v0.w
            + v1.x*v1.x + v1.y*v1.y + v1.z*v1.z + v1.w*v1.w;
    unsigned lo = (unsigned)f2fp8(v0.x) | ((unsigned)f2fp8(v0.y) << 8)
                | ((unsigned)f2fp8(v0.z) << 16) | ((unsigned)f2fp8(v0.w) << 24);
    unsigned hi = (unsigned)f2fp8(v1.x) | ((unsigned)f2fp8(v1.y) << 8)
                | ((unsigned)f2fp8(v1.z) << 16) | ((unsigned)f2fp8(v1.w) << 24);
    *(uint2*)(B8 + (size_t)row * C_ + lane * 8) = make_uint2(lo, hi);
#pragma unroll
    for (int m = 1; m < 64; m <<= 1) s += __shfl_xor(s, m);
    if (lane == 0) cbnorm[row] = s;
}

// ---------------- Kernel 2: A-resident LDS + streamed-B fp8 32x32 MFMA, 8 waves, 4 waves/SIMD ---
// grid = 512 (256 row-strips x 2 col-halves, XCD-chunked); block = 512 (8 waves = 2x4:
// wave = 32 student rows x 64 cb-cols). A 64x512 fp8 = 32KB staged ONCE; B tile 256x64B = 16KB
// double-buffered; cbnorm half staged to LDS (8KB). 64 flat steps, ONE barrier each; stage(t+1)
// right after barrier(t) -> one full step of latency slack. Swapped mfma(cb, student): lane
// holds 32 cb-cols for ONE student row -> in-register epilogue + 1 shfl + direct atomics.
__global__ __launch_bounds__(512, 4) void k2_main(
    const unsigned char* __restrict__ A8,
    const unsigned char* __restrict__ B8,
    const float* __restrict__ xnorm,
    const float* __restrict__ dtg2,
    const float* __restrict__ cbnorm,
    float* __restrict__ s_sum,
    unsigned* __restrict__ minpack)
{
    __shared__ __align__(16) unsigned char aL[32768];      // A: 64 rows x 512B
    __shared__ __align__(16) unsigned char bL[2][16384];   // B: 256 rows x 64B, dbuf
    __shared__ __align__(16) float cbL[2048];              // cbnorm for this col-half
    int tid = threadIdx.x;
    int lane = tid & 63;
    int w = tid >> 6;                    // 0..7
    int wr = w >> 2, wc = w & 3;         // 2 x 4 wave grid
    int l31 = lane & 31;
    int kh = lane >> 5;
    int hk = kh * 8;                     // k-half byte offset

    int orig = blockIdx.x;               // 512 = 8 XCD x 64
    int swz = (orig & 7) * 64 + (orig >> 3);
    int strip = swz >> 1;                // 0..255
    int chalf = swz & 1;
    int row0 = strip * 64;
    int cbase = chalf * 2048;

    // ---- stage A once: granule li: row R=li>>5, LDS granule M=li&31 holds global M^(R&7) ----
#pragma unroll
    for (int i = 0; i < 4; ++i) {
        int li = i * 512 + tid;
        int R = li >> 5;
        int Ms = (li & 31) ^ (R & 7);
        stage16(A8 + (size_t)(row0 + R) * C_ + Ms * 16, aL + li * 16);
    }
    // ---- stage cbnorm half once (2048 floats = 512 granules) ----
    stage16((const char*)cbnorm + (size_t)cbase * 4 + tid * 16, (char*)cbL + tid * 16);

#define STAGE_B(bi, tt_) do {                                                 \
        int cb0_ = cbase + ((tt_) >> 3) * 256;                                \
        int ko_ = ((tt_) & 7) * 64;                                           \
        _Pragma("unroll")                                                     \
        for (int i_ = 0; i_ < 2; ++i_) {                                      \
            int li_ = i_ * 512 + tid;                                         \
            int R_ = li_ >> 2;                                                \
            int G_ = (li_ & 3) ^ ((R_ >> 1) & 3);                             \
            stage16(B8 + (size_t)(cb0_ + R_) * C_ + ko_ + G_ * 16,            \
                    bL[bi] + li_ * 16);                                       \
        }                                                                     \
    } while (0)

    STAGE_B(0, 0);

    int myrow = row0 + wr * 32 + l31;
    float xn = xnorm[myrow];
    float dt = sqrtf(dtg2[myrow]);
    float sv = 0.f;
    unsigned km = 0xFFFFFFFFu;

    f32x16 acc0, acc1;                   // ct = 0 / 1 (32 cb-cols each... 16 regs per 32-col tile)
#pragma unroll
    for (int r = 0; r < 16; ++r) { acc0[r] = 0.f; acc1[r] = 0.f; }

    // read-address constants
    int ax = l31 & 7;                    // A swizzle term (row&7 == l31&7)
    int aB = (wr * 32 + l31) * 512 + hk;
    int bR0 = wc * 64 + l31;             // ct=0 cb-row in tile
    int bR1 = bR0 + 32;                  // ct=1
    int bx0 = (bR0 >> 1) & 3, bx1 = (bR1 >> 1) & 3;
    int bB0 = bR0 * 64 + hk, bB1 = bR1 * 64 + hk;

    for (int cc = 0; cc < 8; ++cc) {
#pragma unroll
        for (int kt = 0; kt < 8; ++kt) {
            int tt = cc * 8 + kt;
            __syncthreads();                      // tile tt landed (implicit vmcnt drain)
            if (tt < 63) STAGE_B((tt + 1) & 1, tt + 1);
            const unsigned char* bT = bL[tt & 1];
            long aF[4], bF0[4], bF1[4];
#pragma unroll
            for (int ksl = 0; ksl < 4; ++ksl) {
                int m = kt * 4 + ksl;
                aF[ksl]  = *(const long*)(aL + aB + ((m ^ ax) * 16));
                bF0[ksl] = *(const long*)(bT + bB0 + ((ksl ^ bx0) * 16));
                bF1[ksl] = *(const long*)(bT + bB1 + ((ksl ^ bx1) * 16));
            }
            __builtin_amdgcn_s_setprio(1);
#pragma unroll
            for (int ksl = 0; ksl < 4; ++ksl) {
                acc0 = __builtin_amdgcn_mfma_f32_32x32x16_fp8_fp8(bF0[ksl], aF[ksl], acc0, 0, 0, 0);
                acc1 = __builtin_amdgcn_mfma_f32_32x32x16_fp8_fp8(bF1[ksl], aF[ksl], acc1, 0, 0, 0);
            }
            __builtin_amdgcn_s_setprio(0);
        }
        // ---- per-cc epilogue: lane = 1 student row x 32 cb-cols; cbn reads broadcast in LDS ----
        int lcS = cc * 256 + wc * 64 + 4 * kh;    // local col base in cbL
#pragma unroll
        for (int r = 0; r < 16; ++r) {
            int cofs = (r & 3) + 8 * (r >> 2);
            {   // ct = 0
                int lc = lcS + cofs;
                float cbn = cbL[lc];
                float d = sqrtf(fmaxf(fmaf(-2.f, acc0[r], xn) + cbn, 0.f));
                sv += __expf(fminf(dt - d, 80.f));
                km = min(km, (__float_as_uint(d) & 0xFFFFF000u) | (unsigned)(cbase + lc));
                acc0[r] = 0.f;
            }
            {   // ct = 1
                int lc = lcS + 32 + cofs;
                float cbn = cbL[lc];
                float d = sqrtf(fmaxf(fmaf(-2.f, acc1[r], xn) + cbn, 0.f));
                sv += __expf(fminf(dt - d, 80.f));
                km = min(km, (__float_as_uint(d) & 0xFFFFF000u) | (unsigned)(cbase + lc));
                acc1[r] = 0.f;
            }
        }
    }
#undef STAGE_B

    // merge k-halves (lane vs lane+32: same row, disjoint cb-col quads)
    sv += __shfl_xor(sv, 32);
    km = min(km, (unsigned)__shfl_xor((int)km, 32));
    if (lane < 32) {
        atomicAdd(&s_sum[myrow], sv);
        atomicMin(&minpack[myrow], km);
    }
}

// ---------------- Kernel 3a: per-token CE/accuracy/emb-loss/target-dist reduce ----------------
__global__ __launch_bounds__(256) void k3a(
    const float* __restrict__ s_sum,
    const unsigned* __restrict__ minpack,
    const int* __restrict__ codes,
    const float* __restrict__ dtg2,
    float* __restrict__ accum)
{
    __shared__ float w0[4], w1[4], w2[4], w3[4];
    int tid = threadIdx.x;
    int n = blockIdx.x * 256 + tid;
    float ce = logf(s_sum[n]);           // = d_t + lse(-d) = per-token CE
    unsigned pred = minpack[n] & 0xFFFu; // col id in the low 12 bits
    float ok = (pred == (unsigned)codes[n]) ? 1.f : 0.f;
    float sq = dtg2[n];
    float td = sqrtf(sq);
#pragma unroll
    for (int m = 1; m < 64; m <<= 1) {
        ce += __shfl_xor(ce, m);
        ok += __shfl_xor(ok, m);
        sq += __shfl_xor(sq, m);
        td += __shfl_xor(td, m);
    }
    int lane = tid & 63, w = tid >> 6;
    if (lane == 0) { w0[w] = ce; w1[w] = ok; w2[w] = sq; w3[w] = td; }
    __syncthreads();
    if (tid == 0) {
        atomicAdd(&accum[0], w0[0] + w0[1] + w0[2] + w0[3]);
        atomicAdd(&accum[1], w1[0] + w1[1] + w1[2] + w1[3]);
        atomicAdd(&accum[2], w2[0] + w2[1] + w2[2] + w2[3]);
        atomicAdd(&accum[3], w3[0] + w3[1] + w3[2] + w3[3]);
    }
}

// ---------------- Kernel 3b: finalize 5 outputs ----------------
__global__ void k3b(const float* __restrict__ accum, float* __restrict__ out)
{
    if (threadIdx.x == 0 && blockIdx.x == 0) {
        float ce   = accum[0] / (float)N_TOK;
        float accy = accum[1] / (float)N_TOK;
        float emb  = accum[2] / ((float)N_TOK * (float)C_);
        float td   = accum[3] / (float)N_TOK;
        out[0] = emb + ce;   // total_loss (EMB_W=CE_W=1)
        out[1] = emb;        // emb_to_codebook_loss
        out[2] = ce;         // ce_loss
        out[3] = accy;       // token_accuracy
        out[4] = td;         // emb_to_target_dist
    }
}

extern "C" void kernel_launch(void* const* d_in, const int* in_sizes, int n_in,
                              void* d_out, int out_size, void* d_ws, size_t ws_size,
                              hipStream_t stream)
{
    const float* student  = (const float*)d_in[0];
    const int*   codes    = (const int*)d_in[1];
    const float* codebook = (const float*)d_in[2];
    // d_in[3] distance_matrix is unused by the reference.
    float* out = (float*)d_out;

    char* ws = (char*)d_ws;
    unsigned char* A8     = (unsigned char*)(ws);                  // 8 MiB
    unsigned char* B8     = (unsigned char*)(ws + 8388608);        // 2 MiB
    float* xnorm          = (float*)(ws + 10485760);               // 64 KiB
    float* dtg2           = (float*)(ws + 10551296);               // 64 KiB
    float* cbnorm         = (float*)(ws + 10616832);               // 16 KiB
    float* s_sum          = (float*)(ws + 10633216);               // 64 KiB
    unsigned* minpack     = (unsigned*)(ws + 10698752);            // 64 KiB
    float* accum          = (float*)(ws + 10829824);               // 64 B

    // k1_cb zero-inits s_sum/minpack/xnorm/dtg2/accum (stream-ordered before k1_prep's atomics)
    hipLaunchKernelGGL(k1_cb, dim3(1024), dim3(256), 0, stream,
                       codebook, B8, cbnorm, s_sum, minpack, xnorm, dtg2, accum);
    hipLaunchKernelGGL(k1_prep, dim3(512), dim3(256), 0, stream,
                       student, codes, codebook, A8, xnorm, dtg2);
    hipLaunchKernelGGL(k2_main, dim3(512), dim3(512), 0, stream,
                       A8, B8, xnorm, dtg2, cbnorm, s_sum, minpack);
    hipLaunchKernelGGL(k3a, dim3(64), dim3(256), 0, stream,
                       s_sum, minpack, codes, dtg2, accum);
    hipLaunchKernelGGL(k3b, dim3(1), dim3(64), 0, stream, accum, out);
}